// Round 1
// baseline (1450.701 us; speedup 1.0000x reference)
//
#include <hip/hip_runtime.h>

#define N_NODES  50000
#define N_EDGES  600000
#define N_GRAPHS 512
#define DIM      128
#define N_FEAT   78
#define N_LAYERS 4
#define BN_EPS   1e-5f

#define SCAN_CHUNK 1024
#define SCAN_NB ((N_NODES + SCAN_CHUNK - 1) / SCAN_CHUNK)  // 49

// ---------------- CSR build ----------------

__global__ __launch_bounds__(256) void count_deg(const int* __restrict__ dst,
                                                 int* __restrict__ deg) {
    int e = blockIdx.x * 256 + threadIdx.x;
    if (e < N_EDGES) atomicAdd(&deg[dst[e]], 1);
}

__global__ __launch_bounds__(256) void scan_a(const int* __restrict__ deg,
                                              int* __restrict__ bsum) {
    __shared__ int sm[256];
    int tid = threadIdx.x;
    int base = blockIdx.x * SCAN_CHUNK + tid * 4;
    int s = 0;
    #pragma unroll
    for (int t = 0; t < 4; ++t) {
        int idx = base + t;
        if (idx < N_NODES) s += deg[idx];
    }
    sm[tid] = s;
    __syncthreads();
    for (int off = 128; off > 0; off >>= 1) {
        if (tid < off) sm[tid] += sm[tid + off];
        __syncthreads();
    }
    if (tid == 0) bsum[blockIdx.x] = sm[0];
}

__global__ void scan_b(const int* __restrict__ bsum, int* __restrict__ bscan) {
    if (threadIdx.x == 0 && blockIdx.x == 0) {
        int run = 0;
        for (int i = 0; i < SCAN_NB; ++i) { bscan[i] = run; run += bsum[i]; }
    }
}

__global__ __launch_bounds__(256) void scan_c(const int* __restrict__ deg,
                                              const int* __restrict__ bscan,
                                              int* __restrict__ off,
                                              int* __restrict__ cur) {
    __shared__ int sm[256];
    int tid = threadIdx.x;
    int base = blockIdx.x * SCAN_CHUNK + tid * 4;
    int v[4];
    int tot = 0;
    #pragma unroll
    for (int t = 0; t < 4; ++t) {
        int idx = base + t;
        v[t] = (idx < N_NODES) ? deg[idx] : 0;
        tot += v[t];
    }
    sm[tid] = tot;
    __syncthreads();
    for (int o = 1; o < 256; o <<= 1) {
        int x = (tid >= o) ? sm[tid - o] : 0;
        __syncthreads();
        sm[tid] += x;
        __syncthreads();
    }
    int exc = sm[tid] - tot + bscan[blockIdx.x];
    #pragma unroll
    for (int t = 0; t < 4; ++t) {
        int idx = base + t;
        if (idx < N_NODES) { off[idx] = exc; cur[idx] = exc; }
        exc += v[t];
    }
}

__global__ __launch_bounds__(256) void fill_csr(const int* __restrict__ src,
                                                const int* __restrict__ dst,
                                                int* __restrict__ cur,
                                                int* __restrict__ csr) {
    int e = blockIdx.x * 256 + threadIdx.x;
    if (e < N_EDGES) {
        int p = atomicAdd(&cur[dst[e]], 1);
        csr[p] = src[e];
    }
}

// ---------------- aggregation: Z[n] = H[n] + sum_{e:dst=n} H[src[e]] ----------------

__global__ __launch_bounds__(256) void aggregate(const float* __restrict__ H,
                                                 const int* __restrict__ off,
                                                 const int* __restrict__ deg,
                                                 const int* __restrict__ csr,
                                                 float* __restrict__ Z) {
    int node = blockIdx.x * 8 + (threadIdx.x >> 5);
    if (node >= N_NODES) return;
    int lane = threadIdx.x & 31;
    const float4* h4 = (const float4*)H;
    float4 v = h4[node * 32 + lane];
    int o = off[node];
    int d = deg[node];
    for (int e = 0; e < d; ++e) {
        int s = csr[o + e];
        float4 u = h4[s * 32 + lane];
        v.x += u.x; v.y += u.y; v.z += u.z; v.w += u.w;
    }
    ((float4*)Z)[node * 32 + lane] = v;
}

// ---------------- GEMM: C[M,128] = act(A[M,K] @ W[K,128] + bias) ----------------
// 64 rows x 128 cols per block, 256 threads, K-chunks of 32 staged in LDS.

template <int RELU>
__global__ __launch_bounds__(256) void gemm_n128(const float* __restrict__ A, int M, int K,
                                                 const float* __restrict__ W,
                                                 const float* __restrict__ bias,
                                                 float* __restrict__ C) {
    __shared__ float As[64 * 32];
    __shared__ float Ws[32 * 128];
    int tid = threadIdx.x;
    int row0 = blockIdx.x * 64;
    int cq = tid & 31;   // column quad: cols cq*4 .. cq*4+3
    int rg = tid >> 5;   // row group 0..7, rows rg*8 .. rg*8+7
    float4 acc[8];
    #pragma unroll
    for (int j = 0; j < 8; ++j) acc[j] = make_float4(0.f, 0.f, 0.f, 0.f);

    for (int k0 = 0; k0 < K; k0 += 32) {
        #pragma unroll
        for (int j = 0; j < 8; ++j) {
            int lin = tid + j * 256;
            int r = lin >> 5, kk = lin & 31;
            int gr = row0 + r, gk = k0 + kk;
            float v = 0.f;
            if (gr < M && gk < K) v = A[gr * K + gk];
            As[r * 32 + kk] = v;
        }
        #pragma unroll
        for (int j = 0; j < 4; ++j) {
            int lin = tid + j * 256;
            int kk = lin >> 5;
            int c = (lin & 31) * 4;
            int gk = k0 + kk;
            float4 v = make_float4(0.f, 0.f, 0.f, 0.f);
            if (gk < K) v = *(const float4*)&W[gk * 128 + c];
            *(float4*)&Ws[kk * 128 + c] = v;
        }
        __syncthreads();
        #pragma unroll
        for (int kk = 0; kk < 32; kk += 4) {
            float4 w0 = *(const float4*)&Ws[(kk + 0) * 128 + cq * 4];
            float4 w1 = *(const float4*)&Ws[(kk + 1) * 128 + cq * 4];
            float4 w2 = *(const float4*)&Ws[(kk + 2) * 128 + cq * 4];
            float4 w3 = *(const float4*)&Ws[(kk + 3) * 128 + cq * 4];
            #pragma unroll
            for (int j = 0; j < 8; ++j) {
                float4 a = *(const float4*)&As[(rg * 8 + j) * 32 + kk];
                acc[j].x += a.x * w0.x + a.y * w1.x + a.z * w2.x + a.w * w3.x;
                acc[j].y += a.x * w0.y + a.y * w1.y + a.z * w2.y + a.w * w3.y;
                acc[j].z += a.x * w0.z + a.y * w1.z + a.z * w2.z + a.w * w3.z;
                acc[j].w += a.x * w0.w + a.y * w1.w + a.z * w2.w + a.w * w3.w;
            }
        }
        __syncthreads();
    }

    float4 b4 = *(const float4*)&bias[cq * 4];
    #pragma unroll
    for (int j = 0; j < 8; ++j) {
        int r = row0 + rg * 8 + j;
        if (r < M) {
            float4 o;
            o.x = acc[j].x + b4.x;
            o.y = acc[j].y + b4.y;
            o.z = acc[j].z + b4.z;
            o.w = acc[j].w + b4.w;
            if (RELU) {
                o.x = fmaxf(o.x, 0.f); o.y = fmaxf(o.y, 0.f);
                o.z = fmaxf(o.z, 0.f); o.w = fmaxf(o.w, 0.f);
            }
            *(float4*)&C[r * 128 + cq * 4] = o;
        }
    }
}

// ---------------- column stats (sum, sumsq per feature) ----------------

__global__ __launch_bounds__(256) void colstats(const float* __restrict__ Z,
                                                float* __restrict__ stats) {
    int tid = threadIdx.x;
    int c = tid & 127;
    int rsub = tid >> 7;  // 0..1
    float s = 0.f, ss = 0.f;
    for (int n = blockIdx.x * 2 + rsub; n < N_NODES; n += gridDim.x * 2) {
        float v = Z[n * DIM + c];
        s += v;
        ss += v * v;
    }
    __shared__ float ls[256], lss[256];
    ls[tid] = s;
    lss[tid] = ss;
    __syncthreads();
    if (tid < 128) {
        atomicAdd(&stats[c], ls[tid] + ls[tid + 128]);
        atomicAdd(&stats[128 + c], lss[tid] + lss[tid + 128]);
    }
}

// ---------------- BN apply + layer-weighted accumulation ----------------

__global__ __launch_bounds__(256) void bn_apply(const float* __restrict__ Z,
                                                const float* __restrict__ stats,
                                                const float* __restrict__ gamma,
                                                const float* __restrict__ beta,
                                                const float* __restrict__ LW, int li,
                                                float* __restrict__ H,
                                                float* __restrict__ Acc) {
    int i = blockIdx.x * 256 + threadIdx.x;  // float4 index
    if (i >= N_NODES * 32) return;
    int c4 = (i & 31) * 4;
    float lwv = LW[li];
    float4 zv = *(const float4*)&Z[i * 4];
    float4 sum = *(const float4*)&stats[c4];
    float4 ssq = *(const float4*)&stats[128 + c4];
    float4 g = *(const float4*)&gamma[c4];
    float4 b = *(const float4*)&beta[c4];
    const float invN = 1.0f / (float)N_NODES;
    float4 hv;
    {
        float m = sum.x * invN; float var = ssq.x * invN - m * m;
        hv.x = (zv.x - m) * rsqrtf(var + BN_EPS) * g.x + b.x;
    }
    {
        float m = sum.y * invN; float var = ssq.y * invN - m * m;
        hv.y = (zv.y - m) * rsqrtf(var + BN_EPS) * g.y + b.y;
    }
    {
        float m = sum.z * invN; float var = ssq.z * invN - m * m;
        hv.z = (zv.z - m) * rsqrtf(var + BN_EPS) * g.z + b.z;
    }
    {
        float m = sum.w * invN; float var = ssq.w * invN - m * m;
        hv.w = (zv.w - m) * rsqrtf(var + BN_EPS) * g.w + b.w;
    }
    *(float4*)&H[i * 4] = hv;
    float4 a = *(const float4*)&Acc[i * 4];
    a.x += lwv * hv.x; a.y += lwv * hv.y; a.z += lwv * hv.z; a.w += lwv * hv.w;
    *(float4*)&Acc[i * 4] = a;
}

// ---------------- pooled output: out[g] = sum_{n in g} (Acc[n] + layer_b) ----------------

__global__ __launch_bounds__(128) void pool(const float* __restrict__ Acc,
                                            const int* __restrict__ batch,
                                            const float* __restrict__ LB,
                                            float* __restrict__ out) {
    int d = threadIdx.x;
    int n0 = blockIdx.x * 128;
    if (n0 >= N_NODES) return;
    int nend = min(n0 + 128, N_NODES);
    float lbv = LB[0];
    int cur = batch[n0];
    float run = 0.f;
    for (int n = n0; n < nend; ++n) {
        int g = batch[n];
        if (g != cur) {
            atomicAdd(&out[cur * DIM + d], run);
            run = 0.f;
            cur = g;
        }
        run += Acc[n * DIM + d] + lbv;
    }
    atomicAdd(&out[cur * DIM + d], run);
}

// ---------------- host launcher ----------------

extern "C" void kernel_launch(void* const* d_in, const int* in_sizes, int n_in,
                              void* d_out, int out_size, void* d_ws, size_t ws_size,
                              hipStream_t stream) {
    const float* x      = (const float*)d_in[0];
    const int*   ei     = (const int*)d_in[1];
    const int*   batch  = (const int*)d_in[2];
    const float* ini_w1 = (const float*)d_in[3];
    const float* ini_b1 = (const float*)d_in[4];
    const float* ini_w2 = (const float*)d_in[5];
    const float* ini_b2 = (const float*)d_in[6];
    const float* gw1    = (const float*)d_in[7];
    const float* gb1    = (const float*)d_in[8];
    const float* gw2    = (const float*)d_in[9];
    const float* gb2    = (const float*)d_in[10];
    const float* gamma  = (const float*)d_in[11];
    const float* beta   = (const float*)d_in[12];
    const float* lw     = (const float*)d_in[13];
    const float* lb     = (const float*)d_in[14];
    float* out = (float*)d_out;

    char* p = (char*)d_ws;
    auto carve = [&](size_t bytes) -> char* {
        char* q = p;
        p += (bytes + 255) & ~(size_t)255;
        return q;
    };
    float* h     = (float*)carve(sizeof(float) * N_NODES * DIM);
    float* z     = (float*)carve(sizeof(float) * N_NODES * DIM);
    float* t     = (float*)carve(sizeof(float) * N_NODES * DIM);
    float* acc   = (float*)carve(sizeof(float) * N_NODES * DIM);
    float* stats = (float*)carve(sizeof(float) * 256);
    int* deg   = (int*)carve(sizeof(int) * N_NODES);
    int* off   = (int*)carve(sizeof(int) * N_NODES);
    int* cur   = (int*)carve(sizeof(int) * N_NODES);
    int* bsum  = (int*)carve(sizeof(int) * 64);
    int* bscan = (int*)carve(sizeof(int) * 64);
    int* csr   = (int*)carve(sizeof(int) * N_EDGES);

    const int* src = ei;
    const int* dst = ei + N_EDGES;

    hipMemsetAsync(deg, 0, sizeof(int) * N_NODES, stream);
    hipMemsetAsync(acc, 0, sizeof(float) * N_NODES * DIM, stream);
    hipMemsetAsync(out, 0, sizeof(float) * N_GRAPHS * DIM, stream);

    count_deg<<<(N_EDGES + 255) / 256, 256, 0, stream>>>(dst, deg);
    scan_a<<<SCAN_NB, 256, 0, stream>>>(deg, bsum);
    scan_b<<<1, 1, 0, stream>>>(bsum, bscan);
    scan_c<<<SCAN_NB, 256, 0, stream>>>(deg, bscan, off, cur);
    fill_csr<<<(N_EDGES + 255) / 256, 256, 0, stream>>>(src, dst, cur, csr);

    int gblocks = (N_NODES + 63) / 64;
    // ini_embed: relu(x @ w1 + b1) @ w2 + b2
    gemm_n128<1><<<gblocks, 256, 0, stream>>>(x, N_NODES, N_FEAT, ini_w1, ini_b1, t);
    gemm_n128<0><<<gblocks, 256, 0, stream>>>(t, N_NODES, DIM, ini_w2, ini_b2, h);

    for (int i = 0; i < N_LAYERS; ++i) {
        aggregate<<<(N_NODES + 7) / 8, 256, 0, stream>>>(h, off, deg, csr, z);
        gemm_n128<1><<<gblocks, 256, 0, stream>>>(z, N_NODES, DIM, gw1 + i * DIM * DIM,
                                                  gb1 + i * DIM, t);
        gemm_n128<1><<<gblocks, 256, 0, stream>>>(t, N_NODES, DIM, gw2 + i * DIM * DIM,
                                                  gb2 + i * DIM, z);
        hipMemsetAsync(stats, 0, sizeof(float) * 256, stream);
        colstats<<<256, 256, 0, stream>>>(z, stats);
        bn_apply<<<(N_NODES * 32 + 255) / 256, 256, 0, stream>>>(
            z, stats, gamma + i * DIM, beta + i * DIM, lw, i, h, acc);
    }
    pool<<<(N_NODES + 127) / 128, 128, 0, stream>>>(acc, batch, lb, out);
}

// Round 3
// 798.816 us; speedup vs baseline: 1.8161x; 1.8161x over previous
//
#include <hip/hip_runtime.h>

#define N_NODES  50000
#define N_EDGES  600000
#define N_GRAPHS 512
#define DIM      128
#define N_FEAT   78
#define N_LAYERS 4
#define BN_EPS   1e-5f

#define SCAN_CHUNK 1024
#define SCAN_NB ((N_NODES + SCAN_CHUNK - 1) / SCAN_CHUNK)  // 49

typedef __attribute__((ext_vector_type(8))) _Float16 f16x8;
typedef __attribute__((ext_vector_type(4))) float f32x4;

static __device__ __forceinline__ short f2h(float f) {
    _Float16 h = (_Float16)f;   // v_cvt_f16_f32, RTN
    union { _Float16 h; short s; } u; u.h = h;
    return u.s;
}

// ---------------- CSR build ----------------

__global__ __launch_bounds__(256) void count_deg(const int* __restrict__ dst,
                                                 int* __restrict__ deg) {
    int e = blockIdx.x * 256 + threadIdx.x;
    if (e < N_EDGES) atomicAdd(&deg[dst[e]], 1);
}

__global__ __launch_bounds__(256) void scan_a(const int* __restrict__ deg,
                                              int* __restrict__ bsum) {
    __shared__ int sm[256];
    int tid = threadIdx.x;
    int base = blockIdx.x * SCAN_CHUNK + tid * 4;
    int s = 0;
    #pragma unroll
    for (int t = 0; t < 4; ++t) {
        int idx = base + t;
        if (idx < N_NODES) s += deg[idx];
    }
    sm[tid] = s;
    __syncthreads();
    for (int off = 128; off > 0; off >>= 1) {
        if (tid < off) sm[tid] += sm[tid + off];
        __syncthreads();
    }
    if (tid == 0) bsum[blockIdx.x] = sm[0];
}

__global__ void scan_b(const int* __restrict__ bsum, int* __restrict__ bscan) {
    if (threadIdx.x == 0 && blockIdx.x == 0) {
        int run = 0;
        for (int i = 0; i < SCAN_NB; ++i) { bscan[i] = run; run += bsum[i]; }
    }
}

__global__ __launch_bounds__(256) void scan_c(const int* __restrict__ deg,
                                              const int* __restrict__ bscan,
                                              int* __restrict__ off,
                                              int* __restrict__ cur) {
    __shared__ int sm[256];
    int tid = threadIdx.x;
    int base = blockIdx.x * SCAN_CHUNK + tid * 4;
    int v[4];
    int tot = 0;
    #pragma unroll
    for (int t = 0; t < 4; ++t) {
        int idx = base + t;
        v[t] = (idx < N_NODES) ? deg[idx] : 0;
        tot += v[t];
    }
    sm[tid] = tot;
    __syncthreads();
    for (int o = 1; o < 256; o <<= 1) {
        int x = (tid >= o) ? sm[tid - o] : 0;
        __syncthreads();
        sm[tid] += x;
        __syncthreads();
    }
    int exc = sm[tid] - tot + bscan[blockIdx.x];
    #pragma unroll
    for (int t = 0; t < 4; ++t) {
        int idx = base + t;
        if (idx < N_NODES) { off[idx] = exc; cur[idx] = exc; }
        exc += v[t];
    }
}

__global__ __launch_bounds__(256) void fill_csr(const int* __restrict__ src,
                                                const int* __restrict__ dst,
                                                int* __restrict__ cur,
                                                int* __restrict__ csr) {
    int e = blockIdx.x * 256 + threadIdx.x;
    if (e < N_EDGES) {
        int p = atomicAdd(&cur[dst[e]], 1);
        csr[p] = src[e];
    }
}

// ---------------- aggregation: Z[n] = H[n] + sum_{e:dst=n} H[src[e]] ----------------

__global__ __launch_bounds__(256) void aggregate(const float* __restrict__ H,
                                                 const int* __restrict__ off,
                                                 const int* __restrict__ deg,
                                                 const int* __restrict__ csr,
                                                 float* __restrict__ Z) {
    int node = blockIdx.x * 8 + (threadIdx.x >> 5);
    if (node >= N_NODES) return;
    int lane = threadIdx.x & 31;
    const float4* h4 = (const float4*)H;
    float4 v = h4[node * 32 + lane];
    int o = off[node];
    int d = deg[node];
    for (int e = 0; e < d; ++e) {
        int s = csr[o + e];
        float4 u = h4[s * 32 + lane];
        v.x += u.x; v.y += u.y; v.z += u.z; v.w += u.w;
    }
    ((float4*)Z)[node * 32 + lane] = v;
}

// ---------------- weight pre-transpose: W[K][128] fp32 -> Wt[n][k] fp16 [128][128] ----
// matrix 0: ini_w1 (78x128, k-padded), 1: ini_w2, 2..5: gin_w1[l], 6..9: gin_w2[l]

__global__ __launch_bounds__(256) void transpose_weights(const float* __restrict__ ini_w1,
                                                         const float* __restrict__ ini_w2,
                                                         const float* __restrict__ gw1,
                                                         const float* __restrict__ gw2,
                                                         short* __restrict__ wt) {
    int gid = blockIdx.x * 256 + threadIdx.x;
    if (gid >= 10 * 16384) return;
    int m = gid >> 14;
    int idx = gid & 16383;
    int n = idx >> 7;
    int k = idx & 127;
    const float* src;
    int K = 128;
    if (m == 0) { src = ini_w1; K = N_FEAT; }
    else if (m == 1) src = ini_w2;
    else if (m < 6) src = gw1 + (m - 2) * 16384;
    else src = gw2 + (m - 6) * 16384;
    float v = (k < K) ? src[k * 128 + n] : 0.f;
    wt[m * 16384 + n * 128 + k] = f2h(v);
}

// ---------------- MFMA GEMM: C[M,128] = act(A[M,K_IN] @ W[K_IN,128] + bias) ----------
// Wt is fp16 [128][128], n-major (k contiguous), k zero-padded to 128.
// Block: 64 rows x 128 cols, 4 waves in 2x2, wave computes 32x64 (2x4 16x16 tiles).

template <int K_IN, int RELU>
__global__ __launch_bounds__(256) void gemm_mfma(const float* __restrict__ A, int M,
                                                 const short* __restrict__ Wt,
                                                 const float* __restrict__ bias,
                                                 float* __restrict__ C) {
    constexpr int LDA = 136;  // padded fp16 row stride (272 B -> bank stride 4)
    __shared__ short As[64 * LDA];
    __shared__ short Ws[128 * LDA];
    int tid = threadIdx.x;
    int row0 = blockIdx.x * 64;

    // stage Wt -> Ws (fp16, already transposed)
    #pragma unroll
    for (int j = 0; j < 8; ++j) {
        int lin = tid + j * 256;      // 2048 chunks of 16B
        int n = lin >> 4;
        int kc = lin & 15;
        uint4 v = *(const uint4*)&Wt[n * 128 + kc * 8];
        *(uint4*)&Ws[n * LDA + kc * 8] = v;
    }
    // stage A -> As (fp32 -> fp16, k zero-padded to 128)
    if (K_IN == 128) {
        #pragma unroll
        for (int j = 0; j < 8; ++j) {
            int lin = tid + j * 256;  // 2048 float4 chunks: 64 rows * 32
            int r = lin >> 5;
            int kq = lin & 31;
            int gr = row0 + r;
            float4 v = make_float4(0.f, 0.f, 0.f, 0.f);
            if (gr < M) v = *(const float4*)&A[gr * 128 + kq * 4];
            short4 s;
            s.x = f2h(v.x); s.y = f2h(v.y); s.z = f2h(v.z); s.w = f2h(v.w);
            *(short4*)&As[r * LDA + kq * 4] = s;
        }
    } else {
        #pragma unroll
        for (int j = 0; j < 32; ++j) {
            int lin = tid + j * 256;  // 8192 elements: 64 rows * 128
            int r = lin >> 7;
            int k = lin & 127;
            int gr = row0 + r;
            float v = 0.f;
            if (gr < M && k < K_IN) v = A[gr * K_IN + k];
            As[r * LDA + k] = f2h(v);
        }
    }
    __syncthreads();

    int wave = tid >> 6;
    int lane = tid & 63;
    int rw = wave >> 1;     // row half: 32 rows
    int cw = wave & 1;      // col half: 64 cols
    int lm = lane & 15;
    int quad = lane >> 4;

    f32x4 acc[2][4];
    #pragma unroll
    for (int mt = 0; mt < 2; ++mt)
        #pragma unroll
        for (int nt = 0; nt < 4; ++nt)
            acc[mt][nt] = (f32x4){0.f, 0.f, 0.f, 0.f};

    #pragma unroll
    for (int ks = 0; ks < 4; ++ks) {
        int kb = ks * 32 + quad * 8;
        f16x8 a0 = *(const f16x8*)&As[(rw * 32 + lm) * LDA + kb];
        f16x8 a1 = *(const f16x8*)&As[(rw * 32 + 16 + lm) * LDA + kb];
        #pragma unroll
        for (int nt = 0; nt < 4; ++nt) {
            f16x8 b = *(const f16x8*)&Ws[(cw * 64 + nt * 16 + lm) * LDA + kb];
            acc[0][nt] = __builtin_amdgcn_mfma_f32_16x16x32_f16(a0, b, acc[0][nt], 0, 0, 0);
            acc[1][nt] = __builtin_amdgcn_mfma_f32_16x16x32_f16(a1, b, acc[1][nt], 0, 0, 0);
        }
    }

    // epilogue: C/D layout col=lane&15, row=quad*4+r
    #pragma unroll
    for (int nt = 0; nt < 4; ++nt) {
        int col = cw * 64 + nt * 16 + lm;
        float bv = bias[col];
        #pragma unroll
        for (int mt = 0; mt < 2; ++mt) {
            #pragma unroll
            for (int r = 0; r < 4; ++r) {
                int row = row0 + rw * 32 + mt * 16 + quad * 4 + r;
                if (row < M) {
                    float o = acc[mt][nt][r] + bv;
                    if (RELU) o = fmaxf(o, 0.f);
                    C[row * 128 + col] = o;
                }
            }
        }
    }
}

// ---------------- column stats (sum, sumsq per feature) ----------------

__global__ __launch_bounds__(256) void colstats(const float* __restrict__ Z,
                                                float* __restrict__ stats) {
    int tid = threadIdx.x;
    int c = tid & 127;
    int rsub = tid >> 7;
    float s = 0.f, ss = 0.f;
    for (int n = blockIdx.x * 2 + rsub; n < N_NODES; n += gridDim.x * 2) {
        float v = Z[n * DIM + c];
        s += v;
        ss += v * v;
    }
    __shared__ float ls[256], lss[256];
    ls[tid] = s;
    lss[tid] = ss;
    __syncthreads();
    if (tid < 128) {
        atomicAdd(&stats[c], ls[tid] + ls[tid + 128]);
        atomicAdd(&stats[128 + c], lss[tid] + lss[tid + 128]);
    }
}

// ---------------- BN apply + layer-weighted accumulation ----------------

__global__ __launch_bounds__(256) void bn_apply(const float* __restrict__ Z,
                                                const float* __restrict__ stats,
                                                const float* __restrict__ gamma,
                                                const float* __restrict__ beta,
                                                const float* __restrict__ LW, int li,
                                                float* __restrict__ H,
                                                float* __restrict__ Acc) {
    int i = blockIdx.x * 256 + threadIdx.x;  // float4 index
    if (i >= N_NODES * 32) return;
    int c4 = (i & 31) * 4;
    float lwv = LW[li];
    float4 zv = *(const float4*)&Z[i * 4];
    float4 sum = *(const float4*)&stats[c4];
    float4 ssq = *(const float4*)&stats[128 + c4];
    float4 g = *(const float4*)&gamma[c4];
    float4 b = *(const float4*)&beta[c4];
    const float invN = 1.0f / (float)N_NODES;
    float4 hv;
    {
        float m = sum.x * invN; float var = ssq.x * invN - m * m;
        hv.x = (zv.x - m) * rsqrtf(var + BN_EPS) * g.x + b.x;
    }
    {
        float m = sum.y * invN; float var = ssq.y * invN - m * m;
        hv.y = (zv.y - m) * rsqrtf(var + BN_EPS) * g.y + b.y;
    }
    {
        float m = sum.z * invN; float var = ssq.z * invN - m * m;
        hv.z = (zv.z - m) * rsqrtf(var + BN_EPS) * g.z + b.z;
    }
    {
        float m = sum.w * invN; float var = ssq.w * invN - m * m;
        hv.w = (zv.w - m) * rsqrtf(var + BN_EPS) * g.w + b.w;
    }
    *(float4*)&H[i * 4] = hv;
    float4 a = *(const float4*)&Acc[i * 4];
    a.x += lwv * hv.x; a.y += lwv * hv.y; a.z += lwv * hv.z; a.w += lwv * hv.w;
    *(float4*)&Acc[i * 4] = a;
}

// ---------------- pooled output ----------------

__global__ __launch_bounds__(128) void pool(const float* __restrict__ Acc,
                                            const int* __restrict__ batch,
                                            const float* __restrict__ LB,
                                            float* __restrict__ out) {
    int d = threadIdx.x;
    int n0 = blockIdx.x * 128;
    if (n0 >= N_NODES) return;
    int nend = min(n0 + 128, N_NODES);
    float lbv = LB[0];
    int cur = batch[n0];
    float run = 0.f;
    for (int n = n0; n < nend; ++n) {
        int g = batch[n];
        if (g != cur) {
            atomicAdd(&out[cur * DIM + d], run);
            run = 0.f;
            cur = g;
        }
        run += Acc[n * DIM + d] + lbv;
    }
    atomicAdd(&out[cur * DIM + d], run);
}

// ---------------- host launcher ----------------

extern "C" void kernel_launch(void* const* d_in, const int* in_sizes, int n_in,
                              void* d_out, int out_size, void* d_ws, size_t ws_size,
                              hipStream_t stream) {
    const float* x      = (const float*)d_in[0];
    const int*   ei     = (const int*)d_in[1];
    const int*   batch  = (const int*)d_in[2];
    const float* ini_w1 = (const float*)d_in[3];
    const float* ini_b1 = (const float*)d_in[4];
    const float* ini_w2 = (const float*)d_in[5];
    const float* ini_b2 = (const float*)d_in[6];
    const float* gw1    = (const float*)d_in[7];
    const float* gb1    = (const float*)d_in[8];
    const float* gw2    = (const float*)d_in[9];
    const float* gb2    = (const float*)d_in[10];
    const float* gamma  = (const float*)d_in[11];
    const float* beta   = (const float*)d_in[12];
    const float* lw     = (const float*)d_in[13];
    const float* lb     = (const float*)d_in[14];
    float* out = (float*)d_out;

    char* p = (char*)d_ws;
    auto carve = [&](size_t bytes) -> char* {
        char* q = p;
        p += (bytes + 255) & ~(size_t)255;
        return q;
    };
    float* h     = (float*)carve(sizeof(float) * N_NODES * DIM);
    float* z     = (float*)carve(sizeof(float) * N_NODES * DIM);
    float* t     = (float*)carve(sizeof(float) * N_NODES * DIM);
    float* acc   = (float*)carve(sizeof(float) * N_NODES * DIM);
    float* stats = (float*)carve(sizeof(float) * 256);
    short* wbf   = (short*)carve(sizeof(short) * 10 * 128 * 128);
    int* deg   = (int*)carve(sizeof(int) * N_NODES);
    int* off   = (int*)carve(sizeof(int) * N_NODES);
    int* cur   = (int*)carve(sizeof(int) * N_NODES);
    int* bsum  = (int*)carve(sizeof(int) * 64);
    int* bscan = (int*)carve(sizeof(int) * 64);
    int* csr   = (int*)carve(sizeof(int) * N_EDGES);

    const int* src = ei;
    const int* dst = ei + N_EDGES;

    hipMemsetAsync(deg, 0, sizeof(int) * N_NODES, stream);
    hipMemsetAsync(acc, 0, sizeof(float) * N_NODES * DIM, stream);
    hipMemsetAsync(out, 0, sizeof(float) * N_GRAPHS * DIM, stream);

    transpose_weights<<<(10 * 16384 + 255) / 256, 256, 0, stream>>>(
        ini_w1, ini_w2, gw1, gw2, wbf);

    count_deg<<<(N_EDGES + 255) / 256, 256, 0, stream>>>(dst, deg);
    scan_a<<<SCAN_NB, 256, 0, stream>>>(deg, bsum);
    scan_b<<<1, 1, 0, stream>>>(bsum, bscan);
    scan_c<<<SCAN_NB, 256, 0, stream>>>(deg, bscan, off, cur);
    fill_csr<<<(N_EDGES + 255) / 256, 256, 0, stream>>>(src, dst, cur, csr);

    int gblocks = (N_NODES + 63) / 64;
    const short* wt_ini1 = wbf;
    const short* wt_ini2 = wbf + 16384;
    // ini_embed: relu(x @ w1 + b1) @ w2 + b2
    gemm_mfma<N_FEAT, 1><<<gblocks, 256, 0, stream>>>(x, N_NODES, wt_ini1, ini_b1, t);
    gemm_mfma<128, 0><<<gblocks, 256, 0, stream>>>(t, N_NODES, wt_ini2, ini_b2, h);

    for (int i = 0; i < N_LAYERS; ++i) {
        const short* wt1 = wbf + (2 + i) * 16384;
        const short* wt2 = wbf + (6 + i) * 16384;
        aggregate<<<(N_NODES + 7) / 8, 256, 0, stream>>>(h, off, deg, csr, z);
        gemm_mfma<128, 1><<<gblocks, 256, 0, stream>>>(z, N_NODES, wt1, gb1 + i * DIM, t);
        gemm_mfma<128, 1><<<gblocks, 256, 0, stream>>>(t, N_NODES, wt2, gb2 + i * DIM, z);
        hipMemsetAsync(stats, 0, sizeof(float) * 256, stream);
        colstats<<<256, 256, 0, stream>>>(z, stats);
        bn_apply<<<(N_NODES * 32 + 255) / 256, 256, 0, stream>>>(
            z, stats, gamma + i * DIM, beta + i * DIM, lw, i, h, acc);
    }
    pool<<<(N_NODES + 127) / 128, 128, 0, stream>>>(acc, batch, lb, out);
}

// Round 4
// 712.594 us; speedup vs baseline: 2.0358x; 1.1210x over previous
//
#include <hip/hip_runtime.h>

#define N_NODES  50000
#define N_EDGES  600000
#define N_GRAPHS 512
#define DIM      128
#define N_FEAT   78
#define N_LAYERS 4
#define BN_EPS   1e-5f

#define SCAN_CHUNK 1024
#define SCAN_NB ((N_NODES + SCAN_CHUNK - 1) / SCAN_CHUNK)  // 49

typedef __attribute__((ext_vector_type(8))) _Float16 f16x8;
typedef __attribute__((ext_vector_type(4))) float f32x4;

static __device__ __forceinline__ short f2h(float f) {
    _Float16 h = (_Float16)f;
    union { _Float16 h; short s; } u; u.h = h;
    return u.s;
}

// ---------------- CSR build ----------------

__global__ __launch_bounds__(256) void count_deg(const int* __restrict__ dst,
                                                 int* __restrict__ deg) {
    int e = blockIdx.x * 256 + threadIdx.x;
    if (e < N_EDGES) atomicAdd(&deg[dst[e]], 1);
}

__global__ __launch_bounds__(256) void gcount(const int* __restrict__ batch,
                                              int* __restrict__ gcnt) {
    int n = blockIdx.x * 256 + threadIdx.x;
    if (n < N_NODES) atomicAdd(&gcnt[batch[n]], 1);
}

__global__ __launch_bounds__(256) void scan_a(const int* __restrict__ deg,
                                              int* __restrict__ bsum) {
    __shared__ int sm[256];
    int tid = threadIdx.x;
    int base = blockIdx.x * SCAN_CHUNK + tid * 4;
    int s = 0;
    #pragma unroll
    for (int t = 0; t < 4; ++t) {
        int idx = base + t;
        if (idx < N_NODES) s += deg[idx];
    }
    sm[tid] = s;
    __syncthreads();
    for (int off = 128; off > 0; off >>= 1) {
        if (tid < off) sm[tid] += sm[tid + off];
        __syncthreads();
    }
    if (tid == 0) bsum[blockIdx.x] = sm[0];
}

__global__ void scan_b(const int* __restrict__ bsum, int* __restrict__ bscan) {
    if (threadIdx.x == 0 && blockIdx.x == 0) {
        int run = 0;
        for (int i = 0; i < SCAN_NB; ++i) { bscan[i] = run; run += bsum[i]; }
    }
}

__global__ __launch_bounds__(256) void scan_c(const int* __restrict__ deg,
                                              const int* __restrict__ bscan,
                                              int* __restrict__ off,
                                              int* __restrict__ cur) {
    __shared__ int sm[256];
    int tid = threadIdx.x;
    int base = blockIdx.x * SCAN_CHUNK + tid * 4;
    int v[4];
    int tot = 0;
    #pragma unroll
    for (int t = 0; t < 4; ++t) {
        int idx = base + t;
        v[t] = (idx < N_NODES) ? deg[idx] : 0;
        tot += v[t];
    }
    sm[tid] = tot;
    __syncthreads();
    for (int o = 1; o < 256; o <<= 1) {
        int x = (tid >= o) ? sm[tid - o] : 0;
        __syncthreads();
        sm[tid] += x;
        __syncthreads();
    }
    int exc = sm[tid] - tot + bscan[blockIdx.x];
    #pragma unroll
    for (int t = 0; t < 4; ++t) {
        int idx = base + t;
        if (idx < N_NODES) { off[idx] = exc; cur[idx] = exc; }
        exc += v[t];
    }
}

__global__ __launch_bounds__(256) void fill_csr(const int* __restrict__ src,
                                                const int* __restrict__ dst,
                                                int* __restrict__ cur,
                                                int* __restrict__ csr) {
    int e = blockIdx.x * 256 + threadIdx.x;
    if (e < N_EDGES) {
        int p = atomicAdd(&cur[dst[e]], 1);
        csr[p] = src[e];
    }
}

// ---------------- affine init: s=1, t=0 ----------------

__global__ void init_affine(float* __restrict__ aff) {
    int d = threadIdx.x;
    aff[d] = 1.0f;
    aff[128 + d] = 0.0f;
}

// ---------------- aggregation with folded BN affine ----------------
// A[n] = s ⊙ (Z[n] + Σ_{j->n} Z[j]) + (1+deg[n]) ⊙ t      (fp16 in/out, fp32 math)

__global__ __launch_bounds__(256) void aggregate_h(const ushort* __restrict__ Z,
                                                   const int* __restrict__ off,
                                                   const int* __restrict__ deg,
                                                   const int* __restrict__ csr,
                                                   const float* __restrict__ aff,
                                                   ushort* __restrict__ A) {
    int node = blockIdx.x * 8 + (threadIdx.x >> 5);
    if (node >= N_NODES) return;
    int lane = threadIdx.x & 31;
    union U { uint2 u; _Float16 h[4]; };
    const uint2* z2 = (const uint2*)Z;   // 4 halves per uint2, 32 per row
    U zu; zu.u = z2[node * 32 + lane];
    float v0 = (float)zu.h[0], v1 = (float)zu.h[1];
    float v2 = (float)zu.h[2], v3 = (float)zu.h[3];
    int o = off[node];
    int d = deg[node];
    for (int e = 0; e < d; ++e) {
        int s = csr[o + e];
        U nu; nu.u = z2[s * 32 + lane];
        v0 += (float)nu.h[0]; v1 += (float)nu.h[1];
        v2 += (float)nu.h[2]; v3 += (float)nu.h[3];
    }
    float4 sa = *(const float4*)&aff[lane * 4];
    float4 ta = *(const float4*)&aff[128 + lane * 4];
    float dsc = 1.0f + (float)d;
    v0 = sa.x * v0 + dsc * ta.x;
    v1 = sa.y * v1 + dsc * ta.y;
    v2 = sa.z * v2 + dsc * ta.z;
    v3 = sa.w * v3 + dsc * ta.w;
    U ou;
    ou.h[0] = (_Float16)v0; ou.h[1] = (_Float16)v1;
    ou.h[2] = (_Float16)v2; ou.h[3] = (_Float16)v3;
    ((uint2*)A)[node * 32 + lane] = ou.u;
}

// ---------------- weight pre-transpose: W[K][128] fp32 -> Wt[n][k] fp16 ----------------

__global__ __launch_bounds__(256) void transpose_weights(const float* __restrict__ ini_w1,
                                                         const float* __restrict__ ini_w2,
                                                         const float* __restrict__ gw1,
                                                         const float* __restrict__ gw2,
                                                         short* __restrict__ wt) {
    int gid = blockIdx.x * 256 + threadIdx.x;
    if (gid >= 10 * 16384) return;
    int m = gid >> 14;
    int idx = gid & 16383;
    int n = idx >> 7;
    int k = idx & 127;
    const float* src;
    int K = 128;
    if (m == 0) { src = ini_w1; K = N_FEAT; }
    else if (m == 1) src = ini_w2;
    else if (m < 6) src = gw1 + (m - 2) * 16384;
    else src = gw2 + (m - 6) * 16384;
    float v = (k < K) ? src[k * 128 + n] : 0.f;
    wt[m * 16384 + n * 128 + k] = f2h(v);
}

// ---------------- MFMA GEMM (fp32 A, K=78, ini layer 1) -> fp16 out ----------------

template <int K_IN, int RELU>
__global__ __launch_bounds__(256) void gemm_f(const float* __restrict__ A,
                                              const short* __restrict__ Wt,
                                              const float* __restrict__ bias,
                                              ushort* __restrict__ C) {
    constexpr int LDA = 136;
    __shared__ short As[64 * LDA];
    __shared__ short Ws[128 * LDA];
    int tid = threadIdx.x;
    int row0 = blockIdx.x * 64;

    #pragma unroll
    for (int j = 0; j < 8; ++j) {
        int lin = tid + j * 256;
        int n = lin >> 4;
        int kc = lin & 15;
        *(uint4*)&Ws[n * LDA + kc * 8] = *(const uint4*)&Wt[n * 128 + kc * 8];
    }
    #pragma unroll
    for (int j = 0; j < 32; ++j) {
        int lin = tid + j * 256;
        int r = lin >> 7;
        int k = lin & 127;
        int gr = row0 + r;
        float v = 0.f;
        if (gr < N_NODES && k < K_IN) v = A[gr * K_IN + k];
        As[r * LDA + k] = f2h(v);
    }
    __syncthreads();

    int wave = tid >> 6;
    int lane = tid & 63;
    int rw = wave >> 1;
    int cw = wave & 1;
    int lm = lane & 15;
    int quad = lane >> 4;

    f32x4 acc[2][4];
    #pragma unroll
    for (int mt = 0; mt < 2; ++mt)
        #pragma unroll
        for (int nt = 0; nt < 4; ++nt)
            acc[mt][nt] = (f32x4){0.f, 0.f, 0.f, 0.f};

    #pragma unroll
    for (int ks = 0; ks < 4; ++ks) {
        int kb = ks * 32 + quad * 8;
        f16x8 a0 = *(const f16x8*)&As[(rw * 32 + lm) * LDA + kb];
        f16x8 a1 = *(const f16x8*)&As[(rw * 32 + 16 + lm) * LDA + kb];
        #pragma unroll
        for (int nt = 0; nt < 4; ++nt) {
            f16x8 b = *(const f16x8*)&Ws[(cw * 64 + nt * 16 + lm) * LDA + kb];
            acc[0][nt] = __builtin_amdgcn_mfma_f32_16x16x32_f16(a0, b, acc[0][nt], 0, 0, 0);
            acc[1][nt] = __builtin_amdgcn_mfma_f32_16x16x32_f16(a1, b, acc[1][nt], 0, 0, 0);
        }
    }

    #pragma unroll
    for (int nt = 0; nt < 4; ++nt) {
        int col = cw * 64 + nt * 16 + lm;
        float bv = bias[col];
        #pragma unroll
        for (int mt = 0; mt < 2; ++mt) {
            #pragma unroll
            for (int r = 0; r < 4; ++r) {
                int row = row0 + rw * 32 + mt * 16 + quad * 4 + r;
                if (row < N_NODES) {
                    float o = acc[mt][nt][r] + bv;
                    if (RELU) o = fmaxf(o, 0.f);
                    C[row * 128 + col] = (ushort)f2h(o);
                }
            }
        }
    }
}

// ---------------- MFMA GEMM (fp16 A, K=128) -> fp16 out ----------------

template <int RELU>
__global__ __launch_bounds__(256) void gemm_h(const ushort* __restrict__ Af,
                                              const short* __restrict__ Wt,
                                              const float* __restrict__ bias,
                                              ushort* __restrict__ C) {
    constexpr int LDA = 136;
    __shared__ short As[64 * LDA];
    __shared__ short Ws[128 * LDA];
    int tid = threadIdx.x;
    int row0 = blockIdx.x * 64;

    #pragma unroll
    for (int j = 0; j < 8; ++j) {
        int lin = tid + j * 256;
        int n = lin >> 4;
        int kc = lin & 15;
        *(uint4*)&Ws[n * LDA + kc * 8] = *(const uint4*)&Wt[n * 128 + kc * 8];
    }
    #pragma unroll
    for (int j = 0; j < 4; ++j) {
        int lin = tid + j * 256;   // 1024 chunks of 16B: 64 rows x 16
        int r = lin >> 4;
        int kc = lin & 15;
        int gr = row0 + r;
        uint4 v = {0u, 0u, 0u, 0u};
        if (gr < N_NODES) v = *(const uint4*)&Af[gr * 128 + kc * 8];
        *(uint4*)&As[r * LDA + kc * 8] = v;
    }
    __syncthreads();

    int wave = tid >> 6;
    int lane = tid & 63;
    int rw = wave >> 1;
    int cw = wave & 1;
    int lm = lane & 15;
    int quad = lane >> 4;

    f32x4 acc[2][4];
    #pragma unroll
    for (int mt = 0; mt < 2; ++mt)
        #pragma unroll
        for (int nt = 0; nt < 4; ++nt)
            acc[mt][nt] = (f32x4){0.f, 0.f, 0.f, 0.f};

    #pragma unroll
    for (int ks = 0; ks < 4; ++ks) {
        int kb = ks * 32 + quad * 8;
        f16x8 a0 = *(const f16x8*)&As[(rw * 32 + lm) * LDA + kb];
        f16x8 a1 = *(const f16x8*)&As[(rw * 32 + 16 + lm) * LDA + kb];
        #pragma unroll
        for (int nt = 0; nt < 4; ++nt) {
            f16x8 b = *(const f16x8*)&Ws[(cw * 64 + nt * 16 + lm) * LDA + kb];
            acc[0][nt] = __builtin_amdgcn_mfma_f32_16x16x32_f16(a0, b, acc[0][nt], 0, 0, 0);
            acc[1][nt] = __builtin_amdgcn_mfma_f32_16x16x32_f16(a1, b, acc[1][nt], 0, 0, 0);
        }
    }

    #pragma unroll
    for (int nt = 0; nt < 4; ++nt) {
        int col = cw * 64 + nt * 16 + lm;
        float bv = bias[col];
        #pragma unroll
        for (int mt = 0; mt < 2; ++mt) {
            #pragma unroll
            for (int r = 0; r < 4; ++r) {
                int row = row0 + rw * 32 + mt * 16 + quad * 4 + r;
                if (row < N_NODES) {
                    float o = acc[mt][nt][r] + bv;
                    if (RELU) o = fmaxf(o, 0.f);
                    C[row * 128 + col] = (ushort)f2h(o);
                }
            }
        }
    }
}

// ---------------- zpool: per-col sum/sumsq (BN stats) + per-graph col sums ----------------

__global__ __launch_bounds__(128) void zpool(const ushort* __restrict__ Z,
                                             const int* __restrict__ batch,
                                             float* __restrict__ stats,
                                             float* __restrict__ gsum) {
    int d = threadIdx.x;
    int n0 = blockIdx.x * 128;
    if (n0 >= N_NODES) return;
    int nend = min(n0 + 128, N_NODES);
    union H { ushort s; _Float16 h; };
    float cs = 0.f, css = 0.f;
    int cur = batch[n0];
    float run = 0.f;
    for (int n = n0; n < nend; ++n) {
        H u; u.s = Z[n * 128 + d];
        float v = (float)u.h;
        cs += v; css += v * v;
        int g = batch[n];
        if (g != cur) {
            atomicAdd(&gsum[cur * 128 + d], run);
            run = 0.f;
            cur = g;
        }
        run += v;
    }
    atomicAdd(&gsum[cur * 128 + d], run);
    atomicAdd(&stats[d], cs);
    atomicAdd(&stats[128 + d], css);
}

// ---------------- finalize: stats -> affine (s, t) ----------------

__global__ void finalize_bn(const float* __restrict__ stats,
                            const float* __restrict__ gamma,
                            const float* __restrict__ beta,
                            float* __restrict__ aff) {
    int d = threadIdx.x;
    const float invN = 1.0f / (float)N_NODES;
    float m = stats[d] * invN;
    float var = stats[128 + d] * invN - m * m;
    float s = gamma[d] * rsqrtf(var + BN_EPS);
    aff[d] = s;
    aff[128 + d] = beta[d] - m * s;
}

// ---------------- combine: out[g,d] = sum_l w_l*(s_l*G_l[g,d] + c_g*t_l) + c_g*lb ------

__global__ __launch_bounds__(256) void combine(const float* __restrict__ gsum,
                                               const float* __restrict__ aff,
                                               const int* __restrict__ gcnt,
                                               const float* __restrict__ LW,
                                               const float* __restrict__ LB,
                                               float* __restrict__ out) {
    int gid = blockIdx.x * 256 + threadIdx.x;
    if (gid >= N_GRAPHS * 128) return;
    int g = gid >> 7;
    int d = gid & 127;
    float c = (float)gcnt[g];
    float o = c * LB[0];
    #pragma unroll
    for (int l = 0; l < N_LAYERS; ++l) {
        float s = aff[(l + 1) * 256 + d];
        float t = aff[(l + 1) * 256 + 128 + d];
        o += LW[l] * (s * gsum[(l * N_GRAPHS + g) * 128 + d] + c * t);
    }
    out[gid] = o;
}

// ---------------- host launcher ----------------

extern "C" void kernel_launch(void* const* d_in, const int* in_sizes, int n_in,
                              void* d_out, int out_size, void* d_ws, size_t ws_size,
                              hipStream_t stream) {
    const float* x      = (const float*)d_in[0];
    const int*   ei     = (const int*)d_in[1];
    const int*   batch  = (const int*)d_in[2];
    const float* ini_w1 = (const float*)d_in[3];
    const float* ini_b1 = (const float*)d_in[4];
    const float* ini_w2 = (const float*)d_in[5];
    const float* ini_b2 = (const float*)d_in[6];
    const float* gw1    = (const float*)d_in[7];
    const float* gb1    = (const float*)d_in[8];
    const float* gw2    = (const float*)d_in[9];
    const float* gb2    = (const float*)d_in[10];
    const float* gamma  = (const float*)d_in[11];
    const float* beta   = (const float*)d_in[12];
    const float* lw     = (const float*)d_in[13];
    const float* lb     = (const float*)d_in[14];
    float* out = (float*)d_out;

    char* p = (char*)d_ws;
    auto carve = [&](size_t bytes) -> char* {
        char* q = p;
        p += (bytes + 255) & ~(size_t)255;
        return q;
    };
    ushort* z0   = (ushort*)carve(sizeof(ushort) * N_NODES * DIM);
    ushort* z1   = (ushort*)carve(sizeof(ushort) * N_NODES * DIM);
    ushort* abuf = (ushort*)carve(sizeof(ushort) * N_NODES * DIM);
    ushort* tbuf = (ushort*)carve(sizeof(ushort) * N_NODES * DIM);
    float* stats = (float*)carve(sizeof(float) * N_LAYERS * 256);
    float* aff   = (float*)carve(sizeof(float) * (N_LAYERS + 1) * 256);
    float* gsum  = (float*)carve(sizeof(float) * N_LAYERS * N_GRAPHS * DIM);
    short* wbf   = (short*)carve(sizeof(short) * 10 * 128 * 128);
    int* gcnt  = (int*)carve(sizeof(int) * N_GRAPHS);
    int* deg   = (int*)carve(sizeof(int) * N_NODES);
    int* off   = (int*)carve(sizeof(int) * N_NODES);
    int* cur   = (int*)carve(sizeof(int) * N_NODES);
    int* bsum  = (int*)carve(sizeof(int) * 64);
    int* bscan = (int*)carve(sizeof(int) * 64);
    int* csr   = (int*)carve(sizeof(int) * N_EDGES);

    const int* src = ei;
    const int* dst = ei + N_EDGES;

    hipMemsetAsync(deg, 0, sizeof(int) * N_NODES, stream);
    hipMemsetAsync(gcnt, 0, sizeof(int) * N_GRAPHS, stream);
    hipMemsetAsync(stats, 0, sizeof(float) * N_LAYERS * 256, stream);
    hipMemsetAsync(gsum, 0, sizeof(float) * N_LAYERS * N_GRAPHS * DIM, stream);

    transpose_weights<<<(10 * 16384 + 255) / 256, 256, 0, stream>>>(
        ini_w1, ini_w2, gw1, gw2, wbf);

    count_deg<<<(N_EDGES + 255) / 256, 256, 0, stream>>>(dst, deg);
    gcount<<<(N_NODES + 255) / 256, 256, 0, stream>>>(batch, gcnt);
    scan_a<<<SCAN_NB, 256, 0, stream>>>(deg, bsum);
    scan_b<<<1, 1, 0, stream>>>(bsum, bscan);
    scan_c<<<SCAN_NB, 256, 0, stream>>>(deg, bscan, off, cur);
    fill_csr<<<(N_EDGES + 255) / 256, 256, 0, stream>>>(src, dst, cur, csr);
    init_affine<<<1, 128, 0, stream>>>(aff);

    int gblocks = (N_NODES + 63) / 64;
    // ini_embed: relu(x @ w1 + b1) @ w2 + b2 -> z0 (fp16)
    gemm_f<N_FEAT, 1><<<gblocks, 256, 0, stream>>>(x, wbf, ini_b1, tbuf);
    gemm_h<0><<<gblocks, 256, 0, stream>>>(tbuf, wbf + 16384, ini_b2, z0);

    ushort* zprev = z0;
    ushort* znext = z1;
    for (int i = 0; i < N_LAYERS; ++i) {
        aggregate_h<<<(N_NODES + 7) / 8, 256, 0, stream>>>(
            zprev, off, deg, csr, aff + i * 256, abuf);
        gemm_h<1><<<gblocks, 256, 0, stream>>>(abuf, wbf + (2 + i) * 16384,
                                               gb1 + i * DIM, tbuf);
        gemm_h<1><<<gblocks, 256, 0, stream>>>(tbuf, wbf + (6 + i) * 16384,
                                               gb2 + i * DIM, znext);
        zpool<<<(N_NODES + 127) / 128, 128, 0, stream>>>(
            znext, batch, stats + i * 256, gsum + i * N_GRAPHS * DIM);
        finalize_bn<<<1, 128, 0, stream>>>(stats + i * 256, gamma + i * DIM,
                                           beta + i * DIM, aff + (i + 1) * 256);
        ushort* tmp = zprev; zprev = znext; znext = tmp;
    }
    combine<<<(N_GRAPHS * 128 + 255) / 256, 256, 0, stream>>>(
        gsum, aff, gcnt, lw, lb, out);
}

// Round 5
// 559.049 us; speedup vs baseline: 2.5949x; 1.2747x over previous
//
#include <hip/hip_runtime.h>

#define N_NODES  50000
#define N_EDGES  600000
#define N_GRAPHS 512
#define DIM      128
#define N_FEAT   78
#define N_LAYERS 4
#define BN_EPS   1e-5f

#define SCAN_CHUNK 1024
#define SCAN_NB ((N_NODES + SCAN_CHUNK - 1) / SCAN_CHUNK)  // 49

typedef __attribute__((ext_vector_type(8))) _Float16 f16x8;
typedef __attribute__((ext_vector_type(4))) float f32x4;

static __device__ __forceinline__ short f2h(float f) {
    _Float16 h = (_Float16)f;
    union { _Float16 h; short s; } u; u.h = h;
    return u.s;
}

// ---------------- CSR build ----------------

__global__ __launch_bounds__(256) void count_deg(const int* __restrict__ dst,
                                                 int* __restrict__ deg) {
    int e = blockIdx.x * 256 + threadIdx.x;
    if (e < N_EDGES) atomicAdd(&deg[dst[e]], 1);
}

__global__ __launch_bounds__(256) void gcount(const int* __restrict__ batch,
                                              int* __restrict__ gcnt) {
    int n = blockIdx.x * 256 + threadIdx.x;
    if (n < N_NODES) atomicAdd(&gcnt[batch[n]], 1);
}

__global__ __launch_bounds__(256) void scan_a(const int* __restrict__ deg,
                                              int* __restrict__ bsum) {
    __shared__ int sm[256];
    int tid = threadIdx.x;
    int base = blockIdx.x * SCAN_CHUNK + tid * 4;
    int s = 0;
    #pragma unroll
    for (int t = 0; t < 4; ++t) {
        int idx = base + t;
        if (idx < N_NODES) s += deg[idx];
    }
    sm[tid] = s;
    __syncthreads();
    for (int off = 128; off > 0; off >>= 1) {
        if (tid < off) sm[tid] += sm[tid + off];
        __syncthreads();
    }
    if (tid == 0) bsum[blockIdx.x] = sm[0];
}

__global__ void scan_b(const int* __restrict__ bsum, int* __restrict__ bscan) {
    if (threadIdx.x == 0 && blockIdx.x == 0) {
        int run = 0;
        for (int i = 0; i < SCAN_NB; ++i) { bscan[i] = run; run += bsum[i]; }
    }
}

__global__ __launch_bounds__(256) void scan_c(const int* __restrict__ deg,
                                              const int* __restrict__ bscan,
                                              int* __restrict__ off,
                                              int* __restrict__ cur) {
    __shared__ int sm[256];
    int tid = threadIdx.x;
    int base = blockIdx.x * SCAN_CHUNK + tid * 4;
    int v[4];
    int tot = 0;
    #pragma unroll
    for (int t = 0; t < 4; ++t) {
        int idx = base + t;
        v[t] = (idx < N_NODES) ? deg[idx] : 0;
        tot += v[t];
    }
    sm[tid] = tot;
    __syncthreads();
    for (int o = 1; o < 256; o <<= 1) {
        int x = (tid >= o) ? sm[tid - o] : 0;
        __syncthreads();
        sm[tid] += x;
        __syncthreads();
    }
    int exc = sm[tid] - tot + bscan[blockIdx.x];
    #pragma unroll
    for (int t = 0; t < 4; ++t) {
        int idx = base + t;
        if (idx < N_NODES) { off[idx] = exc; cur[idx] = exc; }
        exc += v[t];
    }
}

__global__ __launch_bounds__(256) void fill_csr(const int* __restrict__ src,
                                                const int* __restrict__ dst,
                                                int* __restrict__ cur,
                                                int* __restrict__ csr) {
    int e = blockIdx.x * 256 + threadIdx.x;
    if (e < N_EDGES) {
        int p = atomicAdd(&cur[dst[e]], 1);
        csr[p] = src[e];
    }
}

// ---------------- affine init: s=1, t=0 ----------------

__global__ void init_affine(float* __restrict__ aff) {
    int d = threadIdx.x;
    aff[d] = 1.0f;
    aff[128 + d] = 0.0f;
}

// ---------------- aggregation with folded BN affine ----------------
// A[n] = s ⊙ (Z[n] + Σ_{j->n} Z[j]) + (1+deg[n]) ⊙ t      (fp16 in/out, fp32 math)
// 16 lanes x uint4 per node row; edge loop unrolled x4 for gather ILP.

__global__ __launch_bounds__(256) void aggregate_h(const ushort* __restrict__ Z,
                                                   const int* __restrict__ off,
                                                   const int* __restrict__ deg,
                                                   const int* __restrict__ csr,
                                                   const float* __restrict__ aff,
                                                   ushort* __restrict__ A) {
    int node = blockIdx.x * 16 + (threadIdx.x >> 4);
    if (node >= N_NODES) return;
    int lane = threadIdx.x & 15;
    union U { uint4 u; _Float16 h[8]; };
    const uint4* z4 = (const uint4*)Z;   // 8 halves per uint4, 16 per row
    U zu; zu.u = z4[node * 16 + lane];
    float v[8];
    #pragma unroll
    for (int j = 0; j < 8; ++j) v[j] = (float)zu.h[j];
    int o = off[node];
    int d = deg[node];
    int e = 0;
    for (; e + 4 <= d; e += 4) {
        int s0 = csr[o + e + 0], s1 = csr[o + e + 1];
        int s2 = csr[o + e + 2], s3 = csr[o + e + 3];
        U u0, u1, u2, u3;
        u0.u = z4[s0 * 16 + lane];
        u1.u = z4[s1 * 16 + lane];
        u2.u = z4[s2 * 16 + lane];
        u3.u = z4[s3 * 16 + lane];
        #pragma unroll
        for (int j = 0; j < 8; ++j)
            v[j] += ((float)u0.h[j] + (float)u1.h[j]) +
                    ((float)u2.h[j] + (float)u3.h[j]);
    }
    for (; e < d; ++e) {
        int s = csr[o + e];
        U u; u.u = z4[s * 16 + lane];
        #pragma unroll
        for (int j = 0; j < 8; ++j) v[j] += (float)u.h[j];
    }
    float dsc = 1.0f + (float)d;
    U ou;
    #pragma unroll
    for (int j = 0; j < 8; ++j) {
        float s = aff[lane * 8 + j];
        float t = aff[128 + lane * 8 + j];
        ou.h[j] = (_Float16)(s * v[j] + dsc * t);
    }
    ((uint4*)A)[node * 16 + lane] = ou.u;
}

// ---------------- weight pre-transpose: W[K][128] fp32 -> Wt[n][k] fp16 ----------------

__global__ __launch_bounds__(256) void transpose_weights(const float* __restrict__ ini_w1,
                                                         const float* __restrict__ ini_w2,
                                                         const float* __restrict__ gw1,
                                                         const float* __restrict__ gw2,
                                                         short* __restrict__ wt) {
    int gid = blockIdx.x * 256 + threadIdx.x;
    if (gid >= 10 * 16384) return;
    int m = gid >> 14;
    int idx = gid & 16383;
    int n = idx >> 7;
    int k = idx & 127;
    const float* src;
    int K = 128;
    if (m == 0) { src = ini_w1; K = N_FEAT; }
    else if (m == 1) src = ini_w2;
    else if (m < 6) src = gw1 + (m - 2) * 16384;
    else src = gw2 + (m - 6) * 16384;
    float v = (k < K) ? src[k * 128 + n] : 0.f;
    wt[m * 16384 + n * 128 + k] = f2h(v);
}

// ---------------- MFMA GEMM (fp32 A, K=78, ini layer 1) -> fp16 out ----------------

template <int K_IN, int RELU>
__global__ __launch_bounds__(256) void gemm_f(const float* __restrict__ A,
                                              const short* __restrict__ Wt,
                                              const float* __restrict__ bias,
                                              ushort* __restrict__ C) {
    constexpr int LDA = 136;
    __shared__ short As[64 * LDA];
    __shared__ short Ws[128 * LDA];
    int tid = threadIdx.x;
    int row0 = blockIdx.x * 64;

    #pragma unroll
    for (int j = 0; j < 8; ++j) {
        int lin = tid + j * 256;
        int n = lin >> 4;
        int kc = lin & 15;
        *(uint4*)&Ws[n * LDA + kc * 8] = *(const uint4*)&Wt[n * 128 + kc * 8];
    }
    #pragma unroll
    for (int j = 0; j < 32; ++j) {
        int lin = tid + j * 256;
        int r = lin >> 7;
        int k = lin & 127;
        int gr = row0 + r;
        float v = 0.f;
        if (gr < N_NODES && k < K_IN) v = A[gr * K_IN + k];
        As[r * LDA + k] = f2h(v);
    }
    __syncthreads();

    int wave = tid >> 6;
    int lane = tid & 63;
    int rw = wave >> 1;
    int cw = wave & 1;
    int lm = lane & 15;
    int quad = lane >> 4;

    f32x4 acc[2][4];
    #pragma unroll
    for (int mt = 0; mt < 2; ++mt)
        #pragma unroll
        for (int nt = 0; nt < 4; ++nt)
            acc[mt][nt] = (f32x4){0.f, 0.f, 0.f, 0.f};

    #pragma unroll
    for (int ks = 0; ks < 4; ++ks) {
        int kb = ks * 32 + quad * 8;
        f16x8 a0 = *(const f16x8*)&As[(rw * 32 + lm) * LDA + kb];
        f16x8 a1 = *(const f16x8*)&As[(rw * 32 + 16 + lm) * LDA + kb];
        #pragma unroll
        for (int nt = 0; nt < 4; ++nt) {
            f16x8 b = *(const f16x8*)&Ws[(cw * 64 + nt * 16 + lm) * LDA + kb];
            acc[0][nt] = __builtin_amdgcn_mfma_f32_16x16x32_f16(a0, b, acc[0][nt], 0, 0, 0);
            acc[1][nt] = __builtin_amdgcn_mfma_f32_16x16x32_f16(a1, b, acc[1][nt], 0, 0, 0);
        }
    }

    // epilogue: repack via LDS (reuse As), then coalesced uint4 stores
    __syncthreads();
    ushort* Cs = (ushort*)As;
    #pragma unroll
    for (int nt = 0; nt < 4; ++nt) {
        int col = cw * 64 + nt * 16 + lm;
        float bv = bias[col];
        #pragma unroll
        for (int mt = 0; mt < 2; ++mt) {
            #pragma unroll
            for (int r = 0; r < 4; ++r) {
                int row = rw * 32 + mt * 16 + quad * 4 + r;
                float o = acc[mt][nt][r] + bv;
                if (RELU) o = fmaxf(o, 0.f);
                Cs[row * LDA + col] = (ushort)f2h(o);
            }
        }
    }
    __syncthreads();
    #pragma unroll
    for (int j = 0; j < 4; ++j) {
        int lin = tid + j * 256;   // 1024 chunks: 64 rows x 16
        int r = lin >> 4;
        int kc = lin & 15;
        int gr = row0 + r;
        if (gr < N_NODES)
            *(uint4*)&C[gr * 128 + kc * 8] = *(const uint4*)&Cs[r * LDA + kc * 8];
    }
}

// ---------------- MFMA GEMM (fp16 A, K=128) -> fp16 out ----------------

template <int RELU>
__global__ __launch_bounds__(256) void gemm_h(const ushort* __restrict__ Af,
                                              const short* __restrict__ Wt,
                                              const float* __restrict__ bias,
                                              ushort* __restrict__ C) {
    constexpr int LDA = 136;
    __shared__ short As[64 * LDA];
    __shared__ short Ws[128 * LDA];
    int tid = threadIdx.x;
    int row0 = blockIdx.x * 64;

    #pragma unroll
    for (int j = 0; j < 8; ++j) {
        int lin = tid + j * 256;
        int n = lin >> 4;
        int kc = lin & 15;
        *(uint4*)&Ws[n * LDA + kc * 8] = *(const uint4*)&Wt[n * 128 + kc * 8];
    }
    #pragma unroll
    for (int j = 0; j < 4; ++j) {
        int lin = tid + j * 256;   // 1024 chunks of 16B: 64 rows x 16
        int r = lin >> 4;
        int kc = lin & 15;
        int gr = row0 + r;
        uint4 v = {0u, 0u, 0u, 0u};
        if (gr < N_NODES) v = *(const uint4*)&Af[gr * 128 + kc * 8];
        *(uint4*)&As[r * LDA + kc * 8] = v;
    }
    __syncthreads();

    int wave = tid >> 6;
    int lane = tid & 63;
    int rw = wave >> 1;
    int cw = wave & 1;
    int lm = lane & 15;
    int quad = lane >> 4;

    f32x4 acc[2][4];
    #pragma unroll
    for (int mt = 0; mt < 2; ++mt)
        #pragma unroll
        for (int nt = 0; nt < 4; ++nt)
            acc[mt][nt] = (f32x4){0.f, 0.f, 0.f, 0.f};

    #pragma unroll
    for (int ks = 0; ks < 4; ++ks) {
        int kb = ks * 32 + quad * 8;
        f16x8 a0 = *(const f16x8*)&As[(rw * 32 + lm) * LDA + kb];
        f16x8 a1 = *(const f16x8*)&As[(rw * 32 + 16 + lm) * LDA + kb];
        #pragma unroll
        for (int nt = 0; nt < 4; ++nt) {
            f16x8 b = *(const f16x8*)&Ws[(cw * 64 + nt * 16 + lm) * LDA + kb];
            acc[0][nt] = __builtin_amdgcn_mfma_f32_16x16x32_f16(a0, b, acc[0][nt], 0, 0, 0);
            acc[1][nt] = __builtin_amdgcn_mfma_f32_16x16x32_f16(a1, b, acc[1][nt], 0, 0, 0);
        }
    }

    // epilogue: repack via LDS (reuse As), then coalesced uint4 stores
    __syncthreads();
    ushort* Cs = (ushort*)As;
    #pragma unroll
    for (int nt = 0; nt < 4; ++nt) {
        int col = cw * 64 + nt * 16 + lm;
        float bv = bias[col];
        #pragma unroll
        for (int mt = 0; mt < 2; ++mt) {
            #pragma unroll
            for (int r = 0; r < 4; ++r) {
                int row = rw * 32 + mt * 16 + quad * 4 + r;
                float o = acc[mt][nt][r] + bv;
                if (RELU) o = fmaxf(o, 0.f);
                Cs[row * LDA + col] = (ushort)f2h(o);
            }
        }
    }
    __syncthreads();
    #pragma unroll
    for (int j = 0; j < 4; ++j) {
        int lin = tid + j * 256;
        int r = lin >> 4;
        int kc = lin & 15;
        int gr = row0 + r;
        if (gr < N_NODES)
            *(uint4*)&C[gr * 128 + kc * 8] = *(const uint4*)&Cs[r * LDA + kc * 8];
    }
}

// ---------------- zpool: per-col sum/sumsq (BN stats) + per-graph col sums ----------------
// 256 threads: two interleaved row-scans (odd/even) per 128-row chunk.

__global__ __launch_bounds__(256) void zpool(const ushort* __restrict__ Z,
                                             const int* __restrict__ batch,
                                             float* __restrict__ stats,
                                             float* __restrict__ gsum) {
    int d = threadIdx.x & 127;
    int half = threadIdx.x >> 7;
    int n0 = blockIdx.x * 128;
    if (n0 >= N_NODES) return;
    int nend = min(n0 + 128, N_NODES);
    union H { ushort s; _Float16 h; };
    float cs = 0.f, css = 0.f;
    int start = n0 + half;
    if (start < nend) {
        int cur = batch[start];
        float run = 0.f;
        for (int n = start; n < nend; n += 2) {
            H u; u.s = Z[n * 128 + d];
            float v = (float)u.h;
            cs += v; css += v * v;
            int g = batch[n];
            if (g != cur) {
                atomicAdd(&gsum[cur * 128 + d], run);
                run = 0.f;
                cur = g;
            }
            run += v;
        }
        atomicAdd(&gsum[cur * 128 + d], run);
        atomicAdd(&stats[d], cs);
        atomicAdd(&stats[128 + d], css);
    }
}

// ---------------- finalize: stats -> affine (s, t) ----------------

__global__ void finalize_bn(const float* __restrict__ stats,
                            const float* __restrict__ gamma,
                            const float* __restrict__ beta,
                            float* __restrict__ aff) {
    int d = threadIdx.x;
    const float invN = 1.0f / (float)N_NODES;
    float m = stats[d] * invN;
    float var = stats[128 + d] * invN - m * m;
    float s = gamma[d] * rsqrtf(var + BN_EPS);
    aff[d] = s;
    aff[128 + d] = beta[d] - m * s;
}

// ---------------- combine: out[g,d] = sum_l w_l*(s_l*G_l[g,d] + c_g*t_l) + c_g*lb ------

__global__ __launch_bounds__(256) void combine(const float* __restrict__ gsum,
                                               const float* __restrict__ aff,
                                               const int* __restrict__ gcnt,
                                               const float* __restrict__ LW,
                                               const float* __restrict__ LB,
                                               float* __restrict__ out) {
    int gid = blockIdx.x * 256 + threadIdx.x;
    if (gid >= N_GRAPHS * 128) return;
    int g = gid >> 7;
    int d = gid & 127;
    float c = (float)gcnt[g];
    float o = c * LB[0];
    #pragma unroll
    for (int l = 0; l < N_LAYERS; ++l) {
        float s = aff[(l + 1) * 256 + d];
        float t = aff[(l + 1) * 256 + 128 + d];
        o += LW[l] * (s * gsum[(l * N_GRAPHS + g) * 128 + d] + c * t);
    }
    out[gid] = o;
}

// ---------------- host launcher ----------------

extern "C" void kernel_launch(void* const* d_in, const int* in_sizes, int n_in,
                              void* d_out, int out_size, void* d_ws, size_t ws_size,
                              hipStream_t stream) {
    const float* x      = (const float*)d_in[0];
    const int*   ei     = (const int*)d_in[1];
    const int*   batch  = (const int*)d_in[2];
    const float* ini_w1 = (const float*)d_in[3];
    const float* ini_b1 = (const float*)d_in[4];
    const float* ini_w2 = (const float*)d_in[5];
    const float* ini_b2 = (const float*)d_in[6];
    const float* gw1    = (const float*)d_in[7];
    const float* gb1    = (const float*)d_in[8];
    const float* gw2    = (const float*)d_in[9];
    const float* gb2    = (const float*)d_in[10];
    const float* gamma  = (const float*)d_in[11];
    const float* beta   = (const float*)d_in[12];
    const float* lw     = (const float*)d_in[13];
    const float* lb     = (const float*)d_in[14];
    float* out = (float*)d_out;

    char* p = (char*)d_ws;
    auto carve = [&](size_t bytes) -> char* {
        char* q = p;
        p += (bytes + 255) & ~(size_t)255;
        return q;
    };
    ushort* z0   = (ushort*)carve(sizeof(ushort) * N_NODES * DIM);
    ushort* z1   = (ushort*)carve(sizeof(ushort) * N_NODES * DIM);
    ushort* abuf = (ushort*)carve(sizeof(ushort) * N_NODES * DIM);
    ushort* tbuf = (ushort*)carve(sizeof(ushort) * N_NODES * DIM);
    float* stats = (float*)carve(sizeof(float) * N_LAYERS * 256);
    float* aff   = (float*)carve(sizeof(float) * (N_LAYERS + 1) * 256);
    float* gsum  = (float*)carve(sizeof(float) * N_LAYERS * N_GRAPHS * DIM);
    short* wbf   = (short*)carve(sizeof(short) * 10 * 128 * 128);
    int* gcnt  = (int*)carve(sizeof(int) * N_GRAPHS);
    int* deg   = (int*)carve(sizeof(int) * N_NODES);
    int* off   = (int*)carve(sizeof(int) * N_NODES);
    int* cur   = (int*)carve(sizeof(int) * N_NODES);
    int* bsum  = (int*)carve(sizeof(int) * 64);
    int* bscan = (int*)carve(sizeof(int) * 64);
    int* csr   = (int*)carve(sizeof(int) * N_EDGES);

    const int* src = ei;
    const int* dst = ei + N_EDGES;

    hipMemsetAsync(deg, 0, sizeof(int) * N_NODES, stream);
    hipMemsetAsync(gcnt, 0, sizeof(int) * N_GRAPHS, stream);
    hipMemsetAsync(stats, 0, sizeof(float) * N_LAYERS * 256, stream);
    hipMemsetAsync(gsum, 0, sizeof(float) * N_LAYERS * N_GRAPHS * DIM, stream);

    transpose_weights<<<(10 * 16384 + 255) / 256, 256, 0, stream>>>(
        ini_w1, ini_w2, gw1, gw2, wbf);

    count_deg<<<(N_EDGES + 255) / 256, 256, 0, stream>>>(dst, deg);
    gcount<<<(N_NODES + 255) / 256, 256, 0, stream>>>(batch, gcnt);
    scan_a<<<SCAN_NB, 256, 0, stream>>>(deg, bsum);
    scan_b<<<1, 1, 0, stream>>>(bsum, bscan);
    scan_c<<<SCAN_NB, 256, 0, stream>>>(deg, bscan, off, cur);
    fill_csr<<<(N_EDGES + 255) / 256, 256, 0, stream>>>(src, dst, cur, csr);
    init_affine<<<1, 128, 0, stream>>>(aff);

    int gblocks = (N_NODES + 63) / 64;
    // ini_embed: relu(x @ w1 + b1) @ w2 + b2 -> z0 (fp16)
    gemm_f<N_FEAT, 1><<<gblocks, 256, 0, stream>>>(x, wbf, ini_b1, tbuf);
    gemm_h<0><<<gblocks, 256, 0, stream>>>(tbuf, wbf + 16384, ini_b2, z0);

    ushort* zprev = z0;
    ushort* znext = z1;
    for (int i = 0; i < N_LAYERS; ++i) {
        aggregate_h<<<(N_NODES + 15) / 16, 256, 0, stream>>>(
            zprev, off, deg, csr, aff + i * 256, abuf);
        gemm_h<1><<<gblocks, 256, 0, stream>>>(abuf, wbf + (2 + i) * 16384,
                                               gb1 + i * DIM, tbuf);
        gemm_h<1><<<gblocks, 256, 0, stream>>>(tbuf, wbf + (6 + i) * 16384,
                                               gb2 + i * DIM, znext);
        zpool<<<(N_NODES + 127) / 128, 256, 0, stream>>>(
            znext, batch, stats + i * 256, gsum + i * N_GRAPHS * DIM);
        finalize_bn<<<1, 128, 0, stream>>>(stats + i * 256, gamma + i * DIM,
                                           beta + i * DIM, aff + (i + 1) * 256);
        ushort* tmp = zprev; zprev = znext; znext = tmp;
    }
    combine<<<(N_GRAPHS * 128 + 255) / 256, 256, 0, stream>>>(
        gsum, aff, gcnt, lw, lb, out);
}